// Round 12
// baseline (130.702 us; speedup 1.0000x reference)
//
#include <hip/hip_runtime.h>
#include <hip/hip_bf16.h>

#define BB 2
#define NN 1024
#define CC 768
#define HH 12
#define DD 64
#define SCALE_F 0.125f

typedef __attribute__((ext_vector_type(8))) __bf16 bf16x8;
typedef __attribute__((ext_vector_type(8))) unsigned short u16x8;
typedef __attribute__((ext_vector_type(4))) unsigned short u16x4;
typedef __attribute__((ext_vector_type(4))) float f32x4;

static __device__ __forceinline__ bf16x8 as_bf16x8(u16x8 v) {
  return __builtin_bit_cast(bf16x8, v);
}
static __device__ __forceinline__ unsigned short bf16u(float f) {
  __hip_bfloat16 h = __float2bfloat16(f);
  return __builtin_bit_cast(unsigned short, h);
}
// async global->LDS, 16B per lane; LDS dest must be linear in lane order.
static __device__ __forceinline__ void gload16(const void* g, void* l) {
  __builtin_amdgcn_global_load_lds(
      (const __attribute__((address_space(1))) unsigned int*)g,
      (__attribute__((address_space(3))) unsigned int*)l, 16, 0, 0);
}

// ---------------------------------------------------------------------------
// Fused: gate (blocks [0,512)) + fp32->bf16 packs of x/Wqkv/Wproj (rest).
// gate: loga[b,h,n] = (n==0) ? 0 : log2(1-sigmoid(x·Wa^T+ba)), wave per row.
// ---------------------------------------------------------------------------
__global__ __launch_bounds__(256) void packgate(
    const float* __restrict__ x, const float* __restrict__ Wa,
    const float* __restrict__ ba, float* __restrict__ loga,
    unsigned short* __restrict__ xb, int n0,
    const float* __restrict__ Wqkv, unsigned short* __restrict__ wqkvb, int n1,
    const float* __restrict__ Wproj, unsigned short* __restrict__ wprojb,
    int n2) {
  __shared__ float was[HH][CC];  // 36 KB
  if (blockIdx.x < 512) {
    for (int i = threadIdx.x; i < HH * CC; i += 256)
      was[i / CC][i % CC] = Wa[i];
    __syncthreads();
    const int w = threadIdx.x >> 6, lane = threadIdx.x & 63;
    const int row = blockIdx.x * 4 + w;  // 0..2047
    const int b = row >> 10, n = row & 1023;
    const float* xr = x + (size_t)row * CC;
    float xf[12];
#pragma unroll
    for (int j = 0; j < 12; j++) xf[j] = xr[lane + 64 * j];
    float myacc = 0.f;
#pragma unroll
    for (int h = 0; h < HH; h++) {
      float a = 0.f;
#pragma unroll
      for (int j = 0; j < 12; j++) a += xf[j] * was[h][lane + 64 * j];
#pragma unroll
      for (int off = 32; off >= 1; off >>= 1) a += __shfl_xor(a, off, 64);
      if (lane == h) myacc = a;
    }
    if (lane < HH) {
      float acc = myacc + ba[lane];
      float a = 1.f - 1.f / (1.f + __expf(-acc));
      float la = (n == 0) ? 0.f : log2f(a);
      loga[(b * HH + lane) * NN + n] = la;
    }
  } else {
    int i = (blockIdx.x - 512) * 256 + threadIdx.x;
    const float* s;
    unsigned short* d;
    if (i < n0) {
      s = x; d = xb;
    } else if (i < n0 + n1) {
      i -= n0; s = Wqkv; d = wqkvb;
    } else {
      i -= n0 + n1;
      if (i >= n2) return;
      s = Wproj; d = wprojb;
    }
    float4 v = ((const float4*)s)[i];
    u16x4 u = {bf16u(v.x), bf16u(v.y), bf16u(v.z), bf16u(v.w)};
    *(u16x4*)&d[i * 4] = u;
  }
}

// ---------------------------------------------------------------------------
// MFMA GEMM: out = A[M,K] @ W[Nc,K]^T, bf16 in, 2-phase prefetch (T3 min).
// EPI=0: fp32 out + bias.
// EPI=2: fused qkv epilogue — q/k: silu+0.5 + row L2-norm -> qp/kp [B,H,N,D]
//        bf16; v: transposed -> vt [B,H,D,N] bf16. Requires BN=128 (wave owns
//        one full head of 64 cols; row-norm = 16-lane shfl reduce).
// ---------------------------------------------------------------------------
template <int BM, int BN, int EPI>
__global__ __launch_bounds__(256) void gemm_mfma(
    const unsigned short* __restrict__ A, const unsigned short* __restrict__ W,
    const float* __restrict__ bias, void* __restrict__ outv,
    unsigned short* __restrict__ qp, unsigned short* __restrict__ kp,
    unsigned short* __restrict__ vtp, int M, int Nc, int K) {
  __shared__ unsigned short As[2][BM * 64];
  __shared__ unsigned short Ws[2][BN * 64];
  constexpr int FM = BM / 32, FN = BN / 32;
  const int row0 = blockIdx.y * BM;
  const int col0 = blockIdx.x * BN;
  const int t = threadIdx.x;
  const int w = t >> 6, lane = t & 63;
  const int lrow = lane & 15, lgrp = lane >> 4;
  const int wr = w >> 1, wc = w & 1;

  f32x4 acc[FM][FN] = {};

  auto STAGE = [&](int buf, int k0) {
#pragma unroll
    for (int i = 0; i < BM * 8 / 256; i++) {
      int idx = i * 256 + t;
      int row = idx >> 3, sl = (idx & 7) ^ (row & 7);
      gload16(A + (size_t)(row0 + row) * K + k0 + sl * 8, &As[buf][idx * 8]);
    }
#pragma unroll
    for (int i = 0; i < BN * 8 / 256; i++) {
      int idx = i * 256 + t;
      int row = idx >> 3, sl = (idx & 7) ^ (row & 7);
      gload16(W + (size_t)(col0 + row) * K + k0 + sl * 8, &Ws[buf][idx * 8]);
    }
  };

  const int NT = K / 64;
  STAGE(0, 0);
  __syncthreads();

  for (int tt = 0; tt < NT; tt++) {
    const int cur = tt & 1;
    if (tt + 1 < NT) STAGE(cur ^ 1, (tt + 1) * 64);  // prefetch next K-step

    bf16x8 af[FM][2], bf[FN][2];
#pragma unroll
    for (int m = 0; m < FM; m++) {
      int row = wr * (BM / 2) + m * 16 + lrow;
      const u16x8* p = (const u16x8*)&As[cur][row * 64];
#pragma unroll
      for (int hk = 0; hk < 2; hk++)
        af[m][hk] = as_bf16x8(p[(hk * 4 + lgrp) ^ (row & 7)]);
    }
#pragma unroll
    for (int n = 0; n < FN; n++) {
      int row = wc * (BN / 2) + n * 16 + lrow;
      const u16x8* p = (const u16x8*)&Ws[cur][row * 64];
#pragma unroll
      for (int hk = 0; hk < 2; hk++)
        bf[n][hk] = as_bf16x8(p[(hk * 4 + lgrp) ^ (row & 7)]);
    }
#pragma unroll
    for (int m = 0; m < FM; m++)
#pragma unroll
      for (int n = 0; n < FN; n++) {
        acc[m][n] = __builtin_amdgcn_mfma_f32_16x16x32_bf16(
            af[m][0], bf[n][0], acc[m][n], 0, 0, 0);
        acc[m][n] = __builtin_amdgcn_mfma_f32_16x16x32_bf16(
            af[m][1], bf[n][1], acc[m][n], 0, 0, 0);
      }
    __syncthreads();
  }

  if constexpr (EPI == 0) {
#pragma unroll
    for (int n = 0; n < FN; n++) {
      int col = col0 + wc * (BN / 2) + n * 16 + lrow;
      float bb = bias ? bias[col] : 0.f;
#pragma unroll
      for (int m = 0; m < FM; m++) {
        int rbase = row0 + wr * (BM / 2) + m * 16 + lgrp * 4;
#pragma unroll
        for (int r = 0; r < 4; r++)
          ((float*)outv)[(size_t)(rbase + r) * Nc + col] = acc[m][n][r] + bb;
      }
    }
  } else {
    // qkv epilogue. BN==128: wave wc owns one head (64 cols).
    const int sec = col0 / CC;                 // 0=q, 1=k, 2=v
    const int h = ((col0 % CC) >> 6) + wc;     // head index
    const int rb = row0 + wr * (BM / 2);
    const int b = rb >> 10;
    const int nbase = rb & (NN - 1);
    const size_t bh = (size_t)b * HH + h;
    if (sec < 2) {
      unsigned short* dst = sec ? kp : qp;
#pragma unroll
      for (int m = 0; m < FM; m++) {
#pragma unroll
        for (int r = 0; r < 4; r++) {
          float sil[FN];
          float ss = 0.f;
#pragma unroll
          for (int n = 0; n < FN; n++) {
            float v = acc[m][n][r];
            float s = v / (1.f + __expf(-v)) + 0.5f;  // silu(v)+0.5
            sil[n] = s;
            ss += s * s;
          }
#pragma unroll
          for (int off = 1; off <= 8; off <<= 1) ss += __shfl_xor(ss, off, 64);
          float rn = rsqrtf(ss);
          int nn = nbase + m * 16 + lgrp * 4 + r;
#pragma unroll
          for (int n = 0; n < FN; n++)
            dst[(bh * NN + nn) * DD + n * 16 + lrow] = bf16u(sil[n] * rn);
        }
      }
    } else {
#pragma unroll
      for (int m = 0; m < FM; m++) {
#pragma unroll
        for (int n = 0; n < FN; n++) {
          int d = n * 16 + lrow;
          int nn0 = nbase + m * 16 + lgrp * 4;
          u16x4 pkt = {bf16u(acc[m][n][0]), bf16u(acc[m][n][1]),
                       bf16u(acc[m][n][2]), bf16u(acc[m][n][3])};
          *(u16x4*)&vtp[(bh * DD + d) * NN + nn0] = pkt;
        }
      }
    }
  }
}

// ---------------------------------------------------------------------------
// MFMA attention, T14 reg-staged prefetch + T5 setprio.
// Wave 0 scans loga -> cls during tile-0 gload staging (first barrier orders
// both). Loop: issue global loads of tile t+1 into regs BEFORE compute(t)
// (latency hides under QK^T/PV); after the post-compute barrier, ds_write the
// regs into Ks/Vs (swizzled dest, linear source) + barrier. Same barrier
// count as before, zero exposed staging latency after tile 0.
// 4 waves: wq = w&1 Q-half (16 rows), js = w>>1 KV half (8 tiles of 64).
// Cw/Rw alias dead Ks region. LDS 44.1 KB -> 3 blocks/CU. grid = 768.
// ---------------------------------------------------------------------------
__global__ __launch_bounds__(256) void attn_mfma(
    const unsigned short* __restrict__ qp, const unsigned short* __restrict__ kp,
    const unsigned short* __restrict__ vt, const float* __restrict__ loga,
    unsigned short* __restrict__ attnout) {
  __shared__ __align__(16) unsigned char smem[45072];
  unsigned short* Ks = (unsigned short*)smem;            // [2][4096] u16
  unsigned short* Vs = (unsigned short*)(smem + 16384);  // [2][4096] u16
  unsigned short* AwB = (unsigned short*)(smem + 32768); // [4][1024] u16
  float* cls = (float*)(smem + 40960);                   // [1025]
  // post-loop aliases (over Ks/Vs region, dead by then):
  float* CwB = (float*)smem;                             // [2*64][17]
  float* RwB = (float*)(smem + 8704);                    // [2*64][5]

  const int qt2 = blockIdx.x & 31;
  const int bh = blockIdx.x >> 5;
  const int b = bh / HH, h = bh % HH;
  const int qrow0 = qt2 * 32;
  const int w = threadIdx.x >> 6;
  const int lane = threadIdx.x & 63;
  const int lrow = lane & 15;
  const int lgrp = lane >> 4;
  const int wq = w & 1;    // 16-row half of the Q-tile
  const int js = w >> 1;   // KV half

  // ---- wave 0: prefix scan of loga -> cls (c[0]=0, c[m]=sum loga[0..m-1])
  if (w == 0) {
    const float4* s4 = (const float4*)(loga + (size_t)bh * NN + lane * 16);
    float v[16];
#pragma unroll
    for (int q = 0; q < 4; q++) {
      float4 tv = s4[q];
      v[q * 4 + 0] = tv.x; v[q * 4 + 1] = tv.y;
      v[q * 4 + 2] = tv.z; v[q * 4 + 3] = tv.w;
    }
    float run = 0.f;
#pragma unroll
    for (int e = 0; e < 16; e++) { run += v[e]; v[e] = run; }
    float tot = run;
#pragma unroll
    for (int off = 1; off < 64; off <<= 1) {
      float nb = __shfl_up(tot, off, 64);
      if (lane >= off) tot += nb;
    }
    float excl = tot - run;
    if (lane == 0) cls[0] = 0.f;
#pragma unroll
    for (int e = 0; e < 16; e++) cls[1 + lane * 16 + e] = v[e] + excl;
  }

  // ---- prologue: stage tile 0 (both halves) via gload_lds, src pre-swizzled
#pragma unroll
  for (int rep = 0; rep < 4; rep++) {
    int idx = rep * 256 + threadIdx.x;            // 0..1023
    int buf = idx >> 9, row = (idx >> 3) & 63;
    int sl = (idx & 7) ^ (row & 7);
    int j0s = buf * 8 * 64;
    gload16(kp + ((size_t)bh * NN + j0s + row) * DD + sl * 8, Ks + idx * 8);
    gload16(vt + ((size_t)bh * DD + row) * NN + j0s + sl * 8, Vs + idx * 8);
  }

  bf16x8 qaf[2];
  {
    const u16x8* qrow_p = (const u16x8*)(qp +
        ((size_t)bh * NN + qrow0 + wq * 16 + lrow) * DD);
#pragma unroll
    for (int hk = 0; hk < 2; hk++) qaf[hk] = as_bf16x8(qrow_p[hk * 4 + lgrp]);
  }

  const int ibase = qrow0 + wq * 16 + lgrp * 4;
  f32x4 oacc[4] = {};
  float rs[4] = {0.f, 0.f, 0.f, 0.f};

  __syncthreads();  // tile 0 staged; cls ready
  float ci[4], ci1[4];
#pragma unroll
  for (int r = 0; r < 4; r++) {
    ci[r] = cls[ibase + r];
    ci1[r] = cls[ibase + r + 1];
  }

  u16x8 kreg[4], vreg[4];
  for (int t = 0; t < 8; t++) {
    // ---- issue global loads of tile t+1 into regs (hide under compute) ----
    if (t < 7) {
#pragma unroll
      for (int rep = 0; rep < 4; rep++) {
        int idx = rep * 256 + threadIdx.x;
        int buf = idx >> 9, row = (idx >> 3) & 63, slot = idx & 7;
        int j0s = (buf * 8 + t + 1) * 64;
        kreg[rep] =
            *(const u16x8*)(kp + ((size_t)bh * NN + j0s + row) * DD + slot * 8);
        vreg[rep] =
            *(const u16x8*)(vt + ((size_t)bh * DD + row) * NN + j0s + slot * 8);
      }
    }

    const int j0 = (js * 8 + t) * 64;

    // ---- S = Q·K^T per 16-col tile, mask (exp2 of cumsum diff), stash A ----
#pragma unroll
    for (int ct = 0; ct < 4; ct++) {
      const int jl = ct * 16 + lrow;
      const int j = j0 + jl;
      f32x4 s = {};
      const u16x8* krow_p = (const u16x8*)(Ks + js * 4096 + jl * 64);
      __builtin_amdgcn_s_setprio(1);
#pragma unroll
      for (int hk = 0; hk < 2; hk++) {
        bf16x8 kf = as_bf16x8(krow_p[(hk * 4 + lgrp) ^ (jl & 7)]);
        s = __builtin_amdgcn_mfma_f32_16x16x32_bf16(qaf[hk], kf, s, 0, 0, 0);
      }
      __builtin_amdgcn_s_setprio(0);
      const float cj = cls[j], cj1 = cls[j + 1];
#pragma unroll
      for (int r = 0; r < 4; r++) {
        const int gi = ibase + r;
        float m = (gi > j) ? exp2f(ci[r] - cj)
                 : (gi < j) ? exp2f(cj1 - ci1[r]) : 1.0f;
        float av = s[r] * SCALE_F * m;
        rs[r] += av;
        int rowa = lgrp * 4 + r;
        AwB[w * 1024 + rowa * 64 + (jl ^ ((rowa & 7) << 3))] = bf16u(av);
      }
    }

    // ---- O += A·V (Aw stripe is wave-private) ----
    __builtin_amdgcn_s_setprio(1);
#pragma unroll
    for (int jh = 0; jh < 2; jh++) {
      const u16x8* arow_p = (const u16x8*)(AwB + w * 1024 + lrow * 64);
      bf16x8 af = as_bf16x8(arow_p[(jh * 4 + lgrp) ^ (lrow & 7)]);
#pragma unroll
      for (int dt = 0; dt < 4; dt++) {
        const int dd = dt * 16 + lrow;
        const u16x8* vrow_p = (const u16x8*)(Vs + js * 4096 + dd * 64);
        bf16x8 vf = as_bf16x8(vrow_p[(jh * 4 + lgrp) ^ (dd & 7)]);
        oacc[dt] =
            __builtin_amdgcn_mfma_f32_16x16x32_bf16(af, vf, oacc[dt], 0, 0, 0);
      }
    }
    __builtin_amdgcn_s_setprio(0);

    __syncthreads();  // all reads of tile t done

    // ---- write prefetched tile t+1 into LDS (swizzled dest) ----
    if (t < 7) {
#pragma unroll
      for (int rep = 0; rep < 4; rep++) {
        int idx = rep * 256 + threadIdx.x;
        int buf = idx >> 9, row = (idx >> 3) & 63, slot = idx & 7;
        int sw = slot ^ (row & 7);
        *(u16x8*)(Ks + buf * 4096 + row * 64 + sw * 8) = kreg[rep];
        *(u16x8*)(Vs + buf * 4096 + row * 64 + sw * 8) = vreg[rep];
      }
      __syncthreads();  // writes visible before next compute
    }
  }

  // ---- rowsum reduce across the 16 lanes sharing each row ----
#pragma unroll
  for (int r = 0; r < 4; r++) {
#pragma unroll
    for (int off = 1; off <= 8; off <<= 1) rs[r] += __shfl_xor(rs[r], off, 64);
  }

  // ---- combine KV halves (Cw/Rw alias dead Ks region) ----
  if (w >= 2) {
#pragma unroll
    for (int dt = 0; dt < 4; dt++)
#pragma unroll
      for (int r = 0; r < 4; r++)
        CwB[((w - 2) * 64 + lane) * 17 + dt * 4 + r] = oacc[dt][r];
#pragma unroll
    for (int r = 0; r < 4; r++) RwB[((w - 2) * 64 + lane) * 5 + r] = rs[r];
  }
  __syncthreads();
  if (w < 2) {
#pragma unroll
    for (int r = 0; r < 4; r++) {
      rs[r] += RwB[(w * 64 + lane) * 5 + r];
      rs[r] = 1.f / (rs[r] + 1e-6f);
    }
#pragma unroll
    for (int dt = 0; dt < 4; dt++) {
#pragma unroll
      for (int r = 0; r < 4; r++) {
        const int gi = ibase + r;
        float val =
            (oacc[dt][r] + CwB[(w * 64 + lane) * 17 + dt * 4 + r]) * rs[r];
        attnout[((size_t)b * NN + gi) * CC + h * DD + dt * 16 + lrow] =
            bf16u(val);
      }
    }
  }
}

// ---------------------------------------------------------------------------
extern "C" void kernel_launch(void* const* d_in, const int* in_sizes, int n_in,
                              void* d_out, int out_size, void* d_ws,
                              size_t ws_size, hipStream_t stream) {
  const float* x = (const float*)d_in[0];
  const float* Wqkv = (const float*)d_in[1];
  const float* Wa = (const float*)d_in[2];
  const float* ba = (const float*)d_in[3];
  const float* Wproj = (const float*)d_in[4];
  const float* bproj = (const float*)d_in[5];
  float* out = (float*)d_out;

  // workspace layout (~20 MB)
  unsigned short* obuf = (unsigned short*)d_ws;            // B*N*C bf16
  float* loga = (float*)(obuf + (size_t)BB * NN * CC);     // B*H*N f32
  unsigned short* qp = (unsigned short*)(loga + (size_t)BB * HH * NN);
  unsigned short* kp = qp + (size_t)BB * HH * NN * DD;
  unsigned short* vt = kp + (size_t)BB * HH * NN * DD;
  unsigned short* xb = vt + (size_t)BB * HH * NN * DD;
  unsigned short* wqkvb = xb + (size_t)BB * NN * CC;
  unsigned short* wprojb = wqkvb + (size_t)3 * CC * CC;

  const int n0 = BB * NN * CC / 4, n1 = 3 * CC * CC / 4, n2 = CC * CC / 4;

  // A) gate + bf16 packs (one launch)
  packgate<<<512 + (n0 + n1 + n2 + 255) / 256, 256, 0, stream>>>(
      x, Wa, ba, loga, xb, n0, Wqkv, wqkvb, n1, Wproj, wprojb, n2);
  // B) qkv GEMM with fused silu-norm/transpose epilogue -> qp, kp, vt
  {
    dim3 grid(3 * CC / 128, BB * NN / 64);
    gemm_mfma<64, 128, 2><<<grid, 256, 0, stream>>>(
        xb, wqkvb, nullptr, nullptr, qp, kp, vt, BB * NN, 3 * CC, CC);
  }
  // C) MFMA attention (reg-prefetch staged, KV-split, in-block scan) -> obuf
  attn_mfma<<<BB * HH * (NN / 32), 256, 0, stream>>>(qp, kp, vt, loga, obuf);
  // D) out = obuf @ Wproj^T + bproj (2-phase, 64x64 tiles)
  {
    dim3 grid(CC / 64, BB * NN / 64);
    gemm_mfma<64, 64, 0><<<grid, 256, 0, stream>>>(
        obuf, wprojb, bproj, out, nullptr, nullptr, nullptr, BB * NN, CC, CC);
  }
}

// Round 15
// 128.622 us; speedup vs baseline: 1.0162x; 1.0162x over previous
//
#include <hip/hip_runtime.h>
#include <hip/hip_bf16.h>

#define BB 2
#define NN 1024
#define CC 768
#define HH 12
#define DD 64
#define SCALE_F 0.125f

typedef __attribute__((ext_vector_type(8))) __bf16 bf16x8;
typedef __attribute__((ext_vector_type(8))) unsigned short u16x8;
typedef __attribute__((ext_vector_type(4))) unsigned short u16x4;
typedef __attribute__((ext_vector_type(4))) float f32x4;

static __device__ __forceinline__ bf16x8 as_bf16x8(u16x8 v) {
  return __builtin_bit_cast(bf16x8, v);
}
static __device__ __forceinline__ unsigned short bf16u(float f) {
  __hip_bfloat16 h = __float2bfloat16(f);
  return __builtin_bit_cast(unsigned short, h);
}
// async global->LDS, 16B per lane; LDS dest must be linear in lane order.
static __device__ __forceinline__ void gload16(const void* g, void* l) {
  __builtin_amdgcn_global_load_lds(
      (const __attribute__((address_space(1))) unsigned int*)g,
      (__attribute__((address_space(3))) unsigned int*)l, 16, 0, 0);
}

// ---------------------------------------------------------------------------
// Fused: gate + x-pack (blocks [0,512)) + bf16 packs of Wqkv/Wproj (rest).
// gate: loga[b,h,n] = (n==0) ? 0 : log2(1-sigmoid(x·Wa^T+ba)), wave per row.
// Gate blocks also pack their 4 x-rows to bf16 (x already in registers).
// ---------------------------------------------------------------------------
__global__ __launch_bounds__(256) void packgate(
    const float* __restrict__ x, const float* __restrict__ Wa,
    const float* __restrict__ ba, float* __restrict__ loga,
    unsigned short* __restrict__ xb,
    const float* __restrict__ Wqkv, unsigned short* __restrict__ wqkvb, int n1,
    const float* __restrict__ Wproj, unsigned short* __restrict__ wprojb,
    int n2) {
  __shared__ float was[HH][CC];  // 36 KB
  if (blockIdx.x < 512) {
    for (int i = threadIdx.x; i < HH * CC; i += 256)
      was[i / CC][i % CC] = Wa[i];
    __syncthreads();
    const int w = threadIdx.x >> 6, lane = threadIdx.x & 63;
    const int row = blockIdx.x * 4 + w;  // 0..2047
    const int b = row >> 10, n = row & 1023;
    const float* xr = x + (size_t)row * CC;
    float xf[12];
#pragma unroll
    for (int j = 0; j < 12; j++) xf[j] = xr[lane + 64 * j];
    // pack this row to bf16 (reuses the registers)
#pragma unroll
    for (int j = 0; j < 12; j++)
      xb[(size_t)row * CC + lane + 64 * j] = bf16u(xf[j]);
    float myacc = 0.f;
#pragma unroll
    for (int h = 0; h < HH; h++) {
      float a = 0.f;
#pragma unroll
      for (int j = 0; j < 12; j++) a += xf[j] * was[h][lane + 64 * j];
#pragma unroll
      for (int off = 32; off >= 1; off >>= 1) a += __shfl_xor(a, off, 64);
      if (lane == h) myacc = a;
    }
    if (lane < HH) {
      float acc = myacc + ba[lane];
      float a = 1.f - 1.f / (1.f + __expf(-acc));
      float la = (n == 0) ? 0.f : log2f(a);
      loga[(b * HH + lane) * NN + n] = la;
    }
  } else {
    int i = (blockIdx.x - 512) * 256 + threadIdx.x;
    const float* s;
    unsigned short* d;
    if (i < n1) {
      s = Wqkv; d = wqkvb;
    } else {
      i -= n1;
      if (i >= n2) return;
      s = Wproj; d = wprojb;
    }
    float4 v = ((const float4*)s)[i];
    u16x4 u = {bf16u(v.x), bf16u(v.y), bf16u(v.z), bf16u(v.w)};
    *(u16x4*)&d[i * 4] = u;
  }
}

// ---------------------------------------------------------------------------
// MFMA GEMM: out = A[M,K] @ W[Nc,K]^T, bf16 in, 2-phase prefetch (T3 min).
// EPI=0: fp32 out + bias.
// EPI=2: fused qkv epilogue — q/k: silu+0.5 + row L2-norm -> qp/kp [B,H,N,D]
//        bf16; v: transposed -> vt [B,H,D,N] bf16. Requires BN=128 (wave owns
//        one full head of 64 cols; row-norm = 16-lane shfl reduce).
// ---------------------------------------------------------------------------
template <int BM, int BN, int EPI>
__global__ __launch_bounds__(256) void gemm_mfma(
    const unsigned short* __restrict__ A, const unsigned short* __restrict__ W,
    const float* __restrict__ bias, void* __restrict__ outv,
    unsigned short* __restrict__ qp, unsigned short* __restrict__ kp,
    unsigned short* __restrict__ vtp, int M, int Nc, int K) {
  __shared__ unsigned short As[2][BM * 64];
  __shared__ unsigned short Ws[2][BN * 64];
  constexpr int FM = BM / 32, FN = BN / 32;
  const int row0 = blockIdx.y * BM;
  const int col0 = blockIdx.x * BN;
  const int t = threadIdx.x;
  const int w = t >> 6, lane = t & 63;
  const int lrow = lane & 15, lgrp = lane >> 4;
  const int wr = w >> 1, wc = w & 1;

  f32x4 acc[FM][FN] = {};

  auto STAGE = [&](int buf, int k0) {
#pragma unroll
    for (int i = 0; i < BM * 8 / 256; i++) {
      int idx = i * 256 + t;
      int row = idx >> 3, sl = (idx & 7) ^ (row & 7);
      gload16(A + (size_t)(row0 + row) * K + k0 + sl * 8, &As[buf][idx * 8]);
    }
#pragma unroll
    for (int i = 0; i < BN * 8 / 256; i++) {
      int idx = i * 256 + t;
      int row = idx >> 3, sl = (idx & 7) ^ (row & 7);
      gload16(W + (size_t)(col0 + row) * K + k0 + sl * 8, &Ws[buf][idx * 8]);
    }
  };

  const int NT = K / 64;
  STAGE(0, 0);
  __syncthreads();

  for (int tt = 0; tt < NT; tt++) {
    const int cur = tt & 1;
    if (tt + 1 < NT) STAGE(cur ^ 1, (tt + 1) * 64);  // prefetch next K-step

    bf16x8 af[FM][2], bf[FN][2];
#pragma unroll
    for (int m = 0; m < FM; m++) {
      int row = wr * (BM / 2) + m * 16 + lrow;
      const u16x8* p = (const u16x8*)&As[cur][row * 64];
#pragma unroll
      for (int hk = 0; hk < 2; hk++)
        af[m][hk] = as_bf16x8(p[(hk * 4 + lgrp) ^ (row & 7)]);
    }
#pragma unroll
    for (int n = 0; n < FN; n++) {
      int row = wc * (BN / 2) + n * 16 + lrow;
      const u16x8* p = (const u16x8*)&Ws[cur][row * 64];
#pragma unroll
      for (int hk = 0; hk < 2; hk++)
        bf[n][hk] = as_bf16x8(p[(hk * 4 + lgrp) ^ (row & 7)]);
    }
    __builtin_amdgcn_s_setprio(1);
#pragma unroll
    for (int m = 0; m < FM; m++)
#pragma unroll
      for (int n = 0; n < FN; n++) {
        acc[m][n] = __builtin_amdgcn_mfma_f32_16x16x32_bf16(
            af[m][0], bf[n][0], acc[m][n], 0, 0, 0);
        acc[m][n] = __builtin_amdgcn_mfma_f32_16x16x32_bf16(
            af[m][1], bf[n][1], acc[m][n], 0, 0, 0);
      }
    __builtin_amdgcn_s_setprio(0);
    __syncthreads();
  }

  if constexpr (EPI == 0) {
#pragma unroll
    for (int n = 0; n < FN; n++) {
      int col = col0 + wc * (BN / 2) + n * 16 + lrow;
      float bb = bias ? bias[col] : 0.f;
#pragma unroll
      for (int m = 0; m < FM; m++) {
        int rbase = row0 + wr * (BM / 2) + m * 16 + lgrp * 4;
#pragma unroll
        for (int r = 0; r < 4; r++)
          ((float*)outv)[(size_t)(rbase + r) * Nc + col] = acc[m][n][r] + bb;
      }
    }
  } else {
    // qkv epilogue. BN==128: wave wc owns one head (64 cols).
    const int sec = col0 / CC;                 // 0=q, 1=k, 2=v
    const int h = ((col0 % CC) >> 6) + wc;     // head index
    const int rb = row0 + wr * (BM / 2);
    const int b = rb >> 10;
    const int nbase = rb & (NN - 1);
    const size_t bh = (size_t)b * HH + h;
    if (sec < 2) {
      unsigned short* dst = sec ? kp : qp;
#pragma unroll
      for (int m = 0; m < FM; m++) {
#pragma unroll
        for (int r = 0; r < 4; r++) {
          float sil[FN];
          float ss = 0.f;
#pragma unroll
          for (int n = 0; n < FN; n++) {
            float v = acc[m][n][r];
            float s = v / (1.f + __expf(-v)) + 0.5f;  // silu(v)+0.5
            sil[n] = s;
            ss += s * s;
          }
#pragma unroll
          for (int off = 1; off <= 8; off <<= 1) ss += __shfl_xor(ss, off, 64);
          float rn = rsqrtf(ss);
          int nn = nbase + m * 16 + lgrp * 4 + r;
#pragma unroll
          for (int n = 0; n < FN; n++)
            dst[(bh * NN + nn) * DD + n * 16 + lrow] = bf16u(sil[n] * rn);
        }
      }
    } else {
#pragma unroll
      for (int m = 0; m < FM; m++) {
#pragma unroll
        for (int n = 0; n < FN; n++) {
          int d = n * 16 + lrow;
          int nn0 = nbase + m * 16 + lgrp * 4;
          u16x4 pkt = {bf16u(acc[m][n][0]), bf16u(acc[m][n][1]),
                       bf16u(acc[m][n][2]), bf16u(acc[m][n][3])};
          *(u16x4*)&vtp[(bh * DD + d) * NN + nn0] = pkt;
        }
      }
    }
  }
}

// ---------------------------------------------------------------------------
// MFMA attention (gload_lds staged, KV-split, in-block scan prologue).
// Mask: single exp2 with selected argument — diagonal falls out as exp2(0)=1
// (halves the quarter-rate v_exp_f32 count vs predicated two-sided ternary).
// T5 setprio around MFMA clusters. 4 waves: wq = w&1 Q-half, js = w>>1 KV
// half. Cw/Rw alias dead Ks region. LDS 44.1 KB -> 3 blocks/CU. grid = 768.
// ---------------------------------------------------------------------------
__global__ __launch_bounds__(256) void attn_mfma(
    const unsigned short* __restrict__ qp, const unsigned short* __restrict__ kp,
    const unsigned short* __restrict__ vt, const float* __restrict__ loga,
    unsigned short* __restrict__ attnout) {
  __shared__ __align__(16) unsigned char smem[45072];
  unsigned short* Ks = (unsigned short*)smem;            // [2][4096] u16
  unsigned short* Vs = (unsigned short*)(smem + 16384);  // [2][4096] u16
  unsigned short* AwB = (unsigned short*)(smem + 32768); // [4][1024] u16
  float* cls = (float*)(smem + 40960);                   // [1025]
  // post-loop aliases (over Ks/Vs region, dead by then):
  float* CwB = (float*)smem;                             // [2*64][17]
  float* RwB = (float*)(smem + 8704);                    // [2*64][5]

  const int qt2 = blockIdx.x & 31;
  const int bh = blockIdx.x >> 5;
  const int b = bh / HH, h = bh % HH;
  const int qrow0 = qt2 * 32;
  const int w = threadIdx.x >> 6;
  const int lane = threadIdx.x & 63;
  const int lrow = lane & 15;
  const int lgrp = lane >> 4;
  const int wq = w & 1;    // 16-row half of the Q-tile
  const int js = w >> 1;   // KV half

  // ---- wave 0: prefix scan of loga -> cls (c[0]=0, c[m]=sum loga[0..m-1])
  if (w == 0) {
    const float4* s4 = (const float4*)(loga + (size_t)bh * NN + lane * 16);
    float v[16];
#pragma unroll
    for (int q = 0; q < 4; q++) {
      float4 tv = s4[q];
      v[q * 4 + 0] = tv.x; v[q * 4 + 1] = tv.y;
      v[q * 4 + 2] = tv.z; v[q * 4 + 3] = tv.w;
    }
    float run = 0.f;
#pragma unroll
    for (int e = 0; e < 16; e++) { run += v[e]; v[e] = run; }
    float tot = run;
#pragma unroll
    for (int off = 1; off < 64; off <<= 1) {
      float nb = __shfl_up(tot, off, 64);
      if (lane >= off) tot += nb;
    }
    float excl = tot - run;
    if (lane == 0) cls[0] = 0.f;
#pragma unroll
    for (int e = 0; e < 16; e++) cls[1 + lane * 16 + e] = v[e] + excl;
  }

  bf16x8 qaf[2];
  {
    const u16x8* qrow_p = (const u16x8*)(qp +
        ((size_t)bh * NN + qrow0 + wq * 16 + lrow) * DD);
#pragma unroll
    for (int hk = 0; hk < 2; hk++) qaf[hk] = as_bf16x8(qrow_p[hk * 4 + lgrp]);
  }

  const int ibase = qrow0 + wq * 16 + lgrp * 4;
  float ci[4], ci1[4];
  f32x4 oacc[4] = {};
  float rs[4] = {0.f, 0.f, 0.f, 0.f};

  for (int t = 0; t < 8; t++) {
    // ---- stage tiles t (half 0) and t+8 (half 1) via global_load_lds ----
#pragma unroll
    for (int rep = 0; rep < 4; rep++) {
      int idx = rep * 256 + threadIdx.x;          // 0..1023
      int buf = idx >> 9, row = (idx >> 3) & 63;
      int sl = (idx & 7) ^ (row & 7);             // pre-swizzled source slot
      int j0s = (buf * 8 + t) * 64;
      gload16(kp + ((size_t)bh * NN + j0s + row) * DD + sl * 8, Ks + idx * 8);
      gload16(vt + ((size_t)bh * DD + row) * NN + j0s + sl * 8, Vs + idx * 8);
    }
    __syncthreads();
    if (t == 0) {
#pragma unroll
      for (int r = 0; r < 4; r++) {
        ci[r] = cls[ibase + r];
        ci1[r] = cls[ibase + r + 1];
      }
    }

    const int j0 = (js * 8 + t) * 64;

    // ---- S = Q·K^T per 16-col tile, mask, stash A (bf16) ----
#pragma unroll
    for (int ct = 0; ct < 4; ct++) {
      const int jl = ct * 16 + lrow;
      const int j = j0 + jl;
      f32x4 s = {};
      const u16x8* krow_p = (const u16x8*)(Ks + js * 4096 + jl * 64);
      __builtin_amdgcn_s_setprio(1);
#pragma unroll
      for (int hk = 0; hk < 2; hk++) {
        bf16x8 kf = as_bf16x8(krow_p[(hk * 4 + lgrp) ^ (jl & 7)]);
        s = __builtin_amdgcn_mfma_f32_16x16x32_bf16(qaf[hk], kf, s, 0, 0, 0);
      }
      __builtin_amdgcn_s_setprio(0);
      const float cj = cls[j], cj1 = cls[j + 1];
#pragma unroll
      for (int r = 0; r < 4; r++) {
        const int gi = ibase + r;
        // single exp2: diagonal gi==j gives cj1-ci1 = 0 -> exp2(0) = 1.
        float arg = (gi > j) ? (ci[r] - cj) : (cj1 - ci1[r]);
        float av = s[r] * SCALE_F * exp2f(arg);
        rs[r] += av;
        int rowa = lgrp * 4 + r;
        AwB[w * 1024 + rowa * 64 + (jl ^ ((rowa & 7) << 3))] = bf16u(av);
      }
    }

    // ---- O += A·V (Aw stripe is wave-private) ----
    __builtin_amdgcn_s_setprio(1);
#pragma unroll
    for (int jh = 0; jh < 2; jh++) {
      const u16x8* arow_p = (const u16x8*)(AwB + w * 1024 + lrow * 64);
      bf16x8 af = as_bf16x8(arow_p[(jh * 4 + lgrp) ^ (lrow & 7)]);
#pragma unroll
      for (int dt = 0; dt < 4; dt++) {
        const int dd = dt * 16 + lrow;
        const u16x8* vrow_p = (const u16x8*)(Vs + js * 4096 + dd * 64);
        bf16x8 vf = as_bf16x8(vrow_p[(jh * 4 + lgrp) ^ (dd & 7)]);
        oacc[dt] =
            __builtin_amdgcn_mfma_f32_16x16x32_bf16(af, vf, oacc[dt], 0, 0, 0);
      }
    }
    __builtin_amdgcn_s_setprio(0);
    __syncthreads();
  }

  // ---- rowsum reduce across the 16 lanes sharing each row ----
#pragma unroll
  for (int r = 0; r < 4; r++) {
#pragma unroll
    for (int off = 1; off <= 8; off <<= 1) rs[r] += __shfl_xor(rs[r], off, 64);
  }

  // ---- combine KV halves (Cw/Rw alias dead Ks region) ----
  if (w >= 2) {
#pragma unroll
    for (int dt = 0; dt < 4; dt++)
#pragma unroll
      for (int r = 0; r < 4; r++)
        CwB[((w - 2) * 64 + lane) * 17 + dt * 4 + r] = oacc[dt][r];
#pragma unroll
    for (int r = 0; r < 4; r++) RwB[((w - 2) * 64 + lane) * 5 + r] = rs[r];
  }
  __syncthreads();
  if (w < 2) {
#pragma unroll
    for (int r = 0; r < 4; r++) {
      rs[r] += RwB[(w * 64 + lane) * 5 + r];
      rs[r] = 1.f / (rs[r] + 1e-6f);
    }
#pragma unroll
    for (int dt = 0; dt < 4; dt++) {
#pragma unroll
      for (int r = 0; r < 4; r++) {
        const int gi = ibase + r;
        float val =
            (oacc[dt][r] + CwB[(w * 64 + lane) * 17 + dt * 4 + r]) * rs[r];
        attnout[((size_t)b * NN + gi) * CC + h * DD + dt * 16 + lrow] =
            bf16u(val);
      }
    }
  }
}

// ---------------------------------------------------------------------------
extern "C" void kernel_launch(void* const* d_in, const int* in_sizes, int n_in,
                              void* d_out, int out_size, void* d_ws,
                              size_t ws_size, hipStream_t stream) {
  const float* x = (const float*)d_in[0];
  const float* Wqkv = (const float*)d_in[1];
  const float* Wa = (const float*)d_in[2];
  const float* ba = (const float*)d_in[3];
  const float* Wproj = (const float*)d_in[4];
  const float* bproj = (const float*)d_in[5];
  float* out = (float*)d_out;

  // workspace layout (~20 MB)
  unsigned short* obuf = (unsigned short*)d_ws;            // B*N*C bf16
  float* loga = (float*)(obuf + (size_t)BB * NN * CC);     // B*H*N f32
  unsigned short* qp = (unsigned short*)(loga + (size_t)BB * HH * NN);
  unsigned short* kp = qp + (size_t)BB * HH * NN * DD;
  unsigned short* vt = kp + (size_t)BB * HH * NN * DD;
  unsigned short* xb = vt + (size_t)BB * HH * NN * DD;
  unsigned short* wqkvb = xb + (size_t)BB * NN * CC;
  unsigned short* wprojb = wqkvb + (size_t)3 * CC * CC;

  const int n1 = 3 * CC * CC / 4, n2 = CC * CC / 4;

  // A) gate + x-pack + weight packs (one launch)
  packgate<<<512 + (n1 + n2 + 255) / 256, 256, 0, stream>>>(
      x, Wa, ba, loga, xb, Wqkv, wqkvb, n1, Wproj, wprojb, n2);
  // B) qkv GEMM with fused silu-norm/transpose epilogue -> qp, kp, vt
  {
    dim3 grid(3 * CC / 128, BB * NN / 64);
    gemm_mfma<64, 128, 2><<<grid, 256, 0, stream>>>(
        xb, wqkvb, nullptr, nullptr, qp, kp, vt, BB * NN, 3 * CC, CC);
  }
  // C) MFMA attention (staged, KV-split, in-block scan) -> obuf
  attn_mfma<<<BB * HH * (NN / 32), 256, 0, stream>>>(qp, kp, vt, loga, obuf);
  // D) out = obuf @ Wproj^T + bproj (2-phase, 64x64 tiles)
  {
    dim3 grid(CC / 64, BB * NN / 64);
    gemm_mfma<64, 64, 0><<<grid, 256, 0, stream>>>(
        obuf, wprojb, bproj, out, nullptr, nullptr, nullptr, BB * NN, CC, CC);
  }
}